// Round 3
// baseline (361.140 us; speedup 1.0000x reference)
//
#include <hip/hip_runtime.h>
#include <math.h>

// ToneStack: 3 cascaded shelf biquads over x[64, 480000] fp32.
//
// R3: state-composition with CHUNK=64 (was 128).
//   k_zs:    each (row,chunk) runs 64 samples from zero state -> d_k (6 floats).
//   k_scan:  builds A^64 per-block in LDS (6 squarings), then
//            s_k = sum_{m=k-32}^{k-1} A64^{k-1-m} d_m  (Horner, 2048-sample
//            horizon; slowest pole 0.99068^2048 ~ 5e-9).
//   k_apply: re-runs chunk from s_k, stores y (op-for-op DF2T as reference).
// 480000 threads = 7500 waves (~7.3/SIMD) vs R2's 3.7 — R2's streaming
// kernels were still latency-bound on their per-thread serial chains.
// Timed-window fixed overhead (harness poison/restore) ~160 us is out of
// our control; target is kernel sum 150 -> ~85.

constexpr int T_LEN  = 480000;
constexpr int B_ROWS = 64;
constexpr int CHUNK  = 64;              // 2^6 -> 6 squarings
constexpr int LOG2C  = 6;
constexpr int KCH    = T_LEN / CHUNK;   // 7500
constexpr int NC     = B_ROWS * KCH;    // 480000 threads
constexpr int MTERM  = 32;              // 32*64 = 2048-sample history

struct Coeffs { float b0, b1, b2, a1, a2; };

__device__ __forceinline__ Coeffs shelf(float fc, float gdb, float Q) {
    float A  = powf(10.0f, gdb * (1.0f / 40.0f));
    float w0 = 2.0f * 3.14159265358979323846f * fc / 48000.0f;
    float sw = sinf(w0), cw = cosf(w0);
    float alpha = sw / (2.0f * Q);
    float sqA = sqrtf(A);
    float b0 = A * ((A + 1.0f) - (A - 1.0f) * cw + 2.0f * sqA * alpha);
    float b1 = 2.0f * A * ((A - 1.0f) - (A + 1.0f) * cw);
    float b2 = A * ((A + 1.0f) - (A - 1.0f) * cw - 2.0f * sqA * alpha);
    float a0 = (A + 1.0f) + (A - 1.0f) * cw + 2.0f * sqA * alpha;
    float a1 = -2.0f * ((A - 1.0f) + (A + 1.0f) * cw);
    float a2 = (A + 1.0f) + (A - 1.0f) * cw - 2.0f * sqA * alpha;
    float rr = 1.0f / a0;
    Coeffs c;
    c.b0 = b0 * rr; c.b1 = b1 * rr; c.b2 = b2 * rr;
    c.a1 = a1 * rr; c.a2 = a2 * rr;
    return c;
}

// DF2T biquad step, matches reference op-for-op:
__device__ __forceinline__ float bq(float xn, const Coeffs& c, float& z1, float& z2) {
    float y = fmaf(c.b0, xn, z1);
    z1 = fmaf(-c.a1, y, fmaf(c.b1, xn, z2));
    z2 = fmaf(c.b2, xn, -(c.a2 * y));
    return y;
}

__device__ __forceinline__ float step6(float s[6], float x,
                                       const Coeffs& c1, const Coeffs& c2, const Coeffs& c3) {
    float y1 = bq(x,  c1, s[0], s[1]);
    float y2 = bq(y1, c2, s[2], s[3]);
    float y3 = bq(y2, c3, s[4], s[5]);
    return y3;
}

// ---------------- kernel 1: zero-state chunk responses ----------------
__global__ __launch_bounds__(256) void k_zs(
    const float* __restrict__ x,
    const float* __restrict__ p_lg, const float* __restrict__ p_mg,
    const float* __restrict__ p_mf, const float* __restrict__ p_mq,
    const float* __restrict__ p_hg,
    float* __restrict__ dstates)   // SoA: dstates[i*NC + tid]
{
    int tid = blockIdx.x * blockDim.x + threadIdx.x;
    int r = tid / KCH;
    int k = tid - r * KCH;

    Coeffs c1 = shelf(120.0f,  *p_lg, 0.707f);
    Coeffs c2 = shelf(*p_mf,   *p_mg, *p_mq);
    Coeffs c3 = shelf(4000.0f, *p_hg, 0.707f);

    const float* xr = x + (long long)r * T_LEN + (long long)k * CHUNK;
    float s[6] = {0.f,0.f,0.f,0.f,0.f,0.f};

    float4 nxt[8];
    {
        const float4* lp = (const float4*)xr;
        #pragma unroll
        for (int j = 0; j < 8; ++j) nxt[j] = lp[j];
    }
    #pragma unroll
    for (int blk = 0; blk < CHUNK / 32; ++blk) {
        float4 cur[8];
        #pragma unroll
        for (int j = 0; j < 8; ++j) cur[j] = nxt[j];
        if (blk + 1 < CHUNK / 32) {
            const float4* lp = (const float4*)(xr + (blk + 1) * 32);
            #pragma unroll
            for (int j = 0; j < 8; ++j) nxt[j] = lp[j];
        }
        #pragma unroll
        for (int j = 0; j < 8; ++j) {
            float4 v = cur[j];
            step6(s, v.x, c1, c2, c3);
            step6(s, v.y, c1, c2, c3);
            step6(s, v.z, c1, c2, c3);
            step6(s, v.w, c1, c2, c3);
        }
    }
    #pragma unroll
    for (int i = 0; i < 6; ++i) dstates[i * NC + tid] = s[i];
}

// ---------------- kernel 2: per-block A^64 + truncated Horner scan ----------------
__global__ __launch_bounds__(256) void k_scan(
    const float* __restrict__ dstates,
    const float* __restrict__ p_lg, const float* __restrict__ p_mg,
    const float* __restrict__ p_mf, const float* __restrict__ p_mq,
    const float* __restrict__ p_hg,
    float* __restrict__ sstart)    // SoA
{
    __shared__ float M[36];
    int t = threadIdx.x;

    Coeffs c1 = shelf(120.0f,  *p_lg, 0.707f);
    Coeffs c2 = shelf(*p_mf,   *p_mg, *p_mq);
    Coeffs c3 = shelf(4000.0f, *p_hg, 0.707f);

    if (t < 6) {                        // column t of one-sample matrix A
        float s[6] = {0.f,0.f,0.f,0.f,0.f,0.f};
        s[t] = 1.0f;
        step6(s, 0.0f, c1, c2, c3);
        #pragma unroll
        for (int i = 0; i < 6; ++i) M[i * 6 + t] = s[i];
    }
    __syncthreads();
    for (int it = 0; it < LOG2C; ++it) {   // M = A^(2^6) = A^64
        float acc = 0.f;
        if (t < 36) {
            int i = t / 6, j = t % 6;
            #pragma unroll
            for (int q = 0; q < 6; ++q) acc = fmaf(M[i * 6 + q], M[q * 6 + j], acc);
        }
        __syncthreads();
        if (t < 36) M[t] = acc;
        __syncthreads();
    }
    float a[36];
    #pragma unroll
    for (int i = 0; i < 36; ++i) a[i] = M[i];   // LDS broadcast reads

    int tid = blockIdx.x * blockDim.x + t;
    int r = tid / KCH;
    int k = tid - r * KCH;
    int base = tid - k;                 // r*KCH
    int m0 = k - MTERM; if (m0 < 0) m0 = 0;

    float t6[6] = {0.f,0.f,0.f,0.f,0.f,0.f};
    for (int m = m0; m < k; ++m) {
        float dm[6];
        #pragma unroll
        for (int i = 0; i < 6; ++i) dm[i] = dstates[i * NC + base + m];
        float nt[6];
        #pragma unroll
        for (int i = 0; i < 6; ++i) {
            float acc = dm[i];
            #pragma unroll
            for (int j = 0; j < 6; ++j) acc = fmaf(a[i * 6 + j], t6[j], acc);
            nt[i] = acc;
        }
        #pragma unroll
        for (int i = 0; i < 6; ++i) t6[i] = nt[i];
    }
    #pragma unroll
    for (int i = 0; i < 6; ++i) sstart[i * NC + tid] = t6[i];
}

// ---------------- kernel 3: apply with true start states ----------------
__global__ __launch_bounds__(256) void k_apply(
    const float* __restrict__ x,
    const float* __restrict__ p_lg, const float* __restrict__ p_mg,
    const float* __restrict__ p_mf, const float* __restrict__ p_mq,
    const float* __restrict__ p_hg,
    const float* __restrict__ sstart,
    float* __restrict__ out)
{
    int tid = blockIdx.x * blockDim.x + threadIdx.x;
    int r = tid / KCH;
    int k = tid - r * KCH;

    Coeffs c1 = shelf(120.0f,  *p_lg, 0.707f);
    Coeffs c2 = shelf(*p_mf,   *p_mg, *p_mq);
    Coeffs c3 = shelf(4000.0f, *p_hg, 0.707f);

    const float* xr = x   + (long long)r * T_LEN + (long long)k * CHUNK;
    float*       yr = out + (long long)r * T_LEN + (long long)k * CHUNK;

    float s[6];
    #pragma unroll
    for (int i = 0; i < 6; ++i) s[i] = sstart[i * NC + tid];

    float4 nxt[8];
    {
        const float4* lp = (const float4*)xr;
        #pragma unroll
        for (int j = 0; j < 8; ++j) nxt[j] = lp[j];
    }
    #pragma unroll
    for (int blk = 0; blk < CHUNK / 32; ++blk) {
        float4 cur[8];
        #pragma unroll
        for (int j = 0; j < 8; ++j) cur[j] = nxt[j];
        if (blk + 1 < CHUNK / 32) {
            const float4* lp = (const float4*)(xr + (blk + 1) * 32);
            #pragma unroll
            for (int j = 0; j < 8; ++j) nxt[j] = lp[j];
        }
        float4* sp = (float4*)(yr + blk * 32);
        #pragma unroll
        for (int j = 0; j < 8; ++j) {
            float4 v = cur[j];
            float4 o;
            o.x = step6(s, v.x, c1, c2, c3);
            o.y = step6(s, v.y, c1, c2, c3);
            o.z = step6(s, v.z, c1, c2, c3);
            o.w = step6(s, v.w, c1, c2, c3);
            sp[j] = o;
        }
    }
}

// ---------------- fallback: R1 warm-up kernel (if ws too small) ----------------
constexpr int F_CHUNK = 480;
constexpr int F_WARM  = 1536;
constexpr int F_KCH   = T_LEN / F_CHUNK;
constexpr int F_NTHR  = B_ROWS * F_KCH;

__global__ __launch_bounds__(256) void tonestack_fallback(
    const float* __restrict__ x,
    const float* __restrict__ p_lg, const float* __restrict__ p_mg,
    const float* __restrict__ p_mf, const float* __restrict__ p_mq,
    const float* __restrict__ p_hg,
    float* __restrict__ out)
{
    int tid = blockIdx.x * blockDim.x + threadIdx.x;
    if (tid >= F_NTHR) return;
    int r = tid / F_KCH;
    int k = tid - r * F_KCH;

    Coeffs c1 = shelf(120.0f,  *p_lg, 0.707f);
    Coeffs c2 = shelf(*p_mf,   *p_mg, *p_mq);
    Coeffs c3 = shelf(4000.0f, *p_hg, 0.707f);

    const float* xr = x   + (long long)r * T_LEN;
    float*       yr = out + (long long)r * T_LEN;

    int start = k * F_CHUNK;
    int warm  = min(start, F_WARM);
    int p0    = start - warm;
    int nblk  = (warm + F_CHUNK) >> 5;

    float s[6] = {0.f,0.f,0.f,0.f,0.f,0.f};
    float4 nxt[8];
    {
        const float4* lp = (const float4*)(xr + p0);
        #pragma unroll
        for (int j = 0; j < 8; ++j) nxt[j] = lp[j];
    }
    int pos = p0;
    #pragma unroll 1
    for (int blk = 0; blk < nblk; ++blk, pos += 32) {
        float4 cur[8];
        #pragma unroll
        for (int j = 0; j < 8; ++j) cur[j] = nxt[j];
        if (blk + 1 < nblk) {
            const float4* lp = (const float4*)(xr + pos + 32);
            #pragma unroll
            for (int j = 0; j < 8; ++j) nxt[j] = lp[j];
        }
        const bool wr = (pos >= start);
        float4* sp = (float4*)(yr + pos);
        #pragma unroll
        for (int j = 0; j < 8; ++j) {
            float4 v = cur[j];
            float4 o;
            o.x = step6(s, v.x, c1, c2, c3);
            o.y = step6(s, v.y, c1, c2, c3);
            o.z = step6(s, v.z, c1, c2, c3);
            o.w = step6(s, v.w, c1, c2, c3);
            if (wr) sp[j] = o;
        }
    }
}

extern "C" void kernel_launch(void* const* d_in, const int* in_sizes, int n_in,
                              void* d_out, int out_size, void* d_ws, size_t ws_size,
                              hipStream_t stream) {
    const float* x  = (const float*)d_in[0];
    const float* lg = (const float*)d_in[1];
    const float* mg = (const float*)d_in[2];
    const float* mf = (const float*)d_in[3];
    const float* mq = (const float*)d_in[4];
    const float* hg = (const float*)d_in[5];
    float* out = (float*)d_out;

    const size_t need = 2ull * 6 * NC * sizeof(float);
    if (ws_size < need) {
        dim3 grid((F_NTHR + 255) / 256), block(256);
        hipLaunchKernelGGL(tonestack_fallback, grid, block, 0, stream,
                           x, lg, mg, mf, mq, hg, out);
        return;
    }

    float* dstates = (float*)d_ws;
    float* sstart  = dstates + (size_t)6 * NC;

    dim3 block(256);
    dim3 grid(NC / 256);   // 1875, exact

    hipLaunchKernelGGL(k_zs,    grid, block, 0, stream, x, lg, mg, mf, mq, hg, dstates);
    hipLaunchKernelGGL(k_scan,  grid, block, 0, stream, dstates, lg, mg, mf, mq, hg, sstart);
    hipLaunchKernelGGL(k_apply, grid, block, 0, stream, x, lg, mg, mf, mq, hg, sstart, out);
}

// Round 4
// 251.071 us; speedup vs baseline: 1.4384x; 1.4384x over previous
//
#include <hip/hip_runtime.h>
#include <math.h>

// ToneStack: 3 cascaded shelf biquads over x[64, 480000] fp32.
//
// R4: single fused kernel, block-local state composition.
//   Thread t of a block handles one 64-sample chunk (kept in 16xfloat4 regs):
//     1. zero-state pass  -> d_t (6 floats) into LDS
//     2. block computes A^64 (6 LDS squarings), scalarized via readfirstlane
//     3. truncated Horner over 24 predecessor d's (1536-sample horizon,
//        validated by R1: same horizon hit the absmax floor 0.03125)
//     4. re-run chunk from composed start state, burst-store 16 float4s
//        (R3 post-mortem: compute-interleaved 16B stores at 256B/thread grain
//         caused 2.1x HBM write amplification via partial-dirty L2 evictions;
//         the tight store burst closes the dirty window).
//   Block = 24 history chunks + 232 output chunks; blocks overlap by 24
//   chunks (1.10x read amp). No workspace, no cross-block communication.

constexpr int T_LEN  = 480000;
constexpr int B_ROWS = 64;
constexpr int CHUNK  = 64;
constexpr int LOG2C  = 6;                     // A^64 = 6 squarings
constexpr int KCH    = T_LEN / CHUNK;         // 7500 chunks per row
constexpr int NT     = 256;                   // threads per block
constexpr int HISTC  = 24;                    // history chunks (1536 samples)
constexpr int MTERM  = 24;                    // Horner terms (= horizon)
constexpr int OUTC   = NT - HISTC;            // 232 output chunks per block
constexpr int BLKROW = (KCH + OUTC - 1) / OUTC;  // 33 blocks per row
constexpr int NBLK   = B_ROWS * BLKROW;       // 2112 blocks

struct Coeffs { float b0, b1, b2, a1, a2; };

__device__ __forceinline__ float rfl(float v) {
    return __int_as_float(__builtin_amdgcn_readfirstlane(__float_as_int(v)));
}

__device__ __forceinline__ Coeffs shelf(float fc, float gdb, float Q) {
    float A  = powf(10.0f, gdb * (1.0f / 40.0f));
    float w0 = 2.0f * 3.14159265358979323846f * fc / 48000.0f;
    float sw = sinf(w0), cw = cosf(w0);
    float alpha = sw / (2.0f * Q);
    float sqA = sqrtf(A);
    float b0 = A * ((A + 1.0f) - (A - 1.0f) * cw + 2.0f * sqA * alpha);
    float b1 = 2.0f * A * ((A - 1.0f) - (A + 1.0f) * cw);
    float b2 = A * ((A + 1.0f) - (A - 1.0f) * cw - 2.0f * sqA * alpha);
    float a0 = (A + 1.0f) + (A - 1.0f) * cw + 2.0f * sqA * alpha;
    float a1 = -2.0f * ((A - 1.0f) + (A + 1.0f) * cw);
    float a2 = (A + 1.0f) + (A - 1.0f) * cw - 2.0f * sqA * alpha;
    float rr = 1.0f / a0;
    Coeffs c;
    c.b0 = rfl(b0 * rr); c.b1 = rfl(b1 * rr); c.b2 = rfl(b2 * rr);
    c.a1 = rfl(a1 * rr); c.a2 = rfl(a2 * rr);
    return c;
}

// DF2T biquad step, op-for-op as reference:
//   y = b0*x + z1; z1' = b1*x - a1*y + z2; z2' = b2*x - a2*y
__device__ __forceinline__ float bq(float xn, const Coeffs& c, float& z1, float& z2) {
    float y = fmaf(c.b0, xn, z1);
    z1 = fmaf(-c.a1, y, fmaf(c.b1, xn, z2));
    z2 = fmaf(c.b2, xn, -(c.a2 * y));
    return y;
}

__device__ __forceinline__ float step6(float s[6], float x,
                                       const Coeffs& c1, const Coeffs& c2, const Coeffs& c3) {
    float y1 = bq(x,  c1, s[0], s[1]);
    float y2 = bq(y1, c2, s[2], s[3]);
    float y3 = bq(y2, c3, s[4], s[5]);
    return y3;
}

__global__ __launch_bounds__(256, 4) void k_fused(
    const float* __restrict__ x,
    const float* __restrict__ p_lg, const float* __restrict__ p_mg,
    const float* __restrict__ p_mf, const float* __restrict__ p_mq,
    const float* __restrict__ p_hg,
    float* __restrict__ out)
{
    __shared__ float dl[NT * 7];   // per-thread d, stride 7 (conflict-free)
    __shared__ float M[36];        // A^64 workspace

    const int t = threadIdx.x;
    const int r = blockIdx.x / BLKROW;
    const int b = blockIdx.x - r * BLKROW;
    const int c = b * OUTC + t - HISTC;          // this thread's chunk index
    const bool active = (c >= 0) && (c < KCH);
    const bool emit   = (t >= HISTC) && (c < KCH);

    Coeffs c1 = shelf(120.0f,  *p_lg, 0.707f);
    Coeffs c2 = shelf(*p_mf,   *p_mg, *p_mq);
    Coeffs c3 = shelf(4000.0f, *p_hg, 0.707f);

    // ---- load chunk into registers ----
    float4 xv[16];
    {
        int cc = c < 0 ? 0 : c;
        const float4* lp = (const float4*)(x + (long long)r * T_LEN + (long long)cc * CHUNK);
        if (active) {
            #pragma unroll
            for (int q = 0; q < 16; ++q) xv[q] = lp[q];
        } else {
            #pragma unroll
            for (int q = 0; q < 16; ++q) xv[q] = make_float4(0.f, 0.f, 0.f, 0.f);
        }
    }

    // ---- pass 1: zero-state response of this chunk ----
    float s[6] = {0.f, 0.f, 0.f, 0.f, 0.f, 0.f};
    #pragma unroll
    for (int q = 0; q < 16; ++q) {
        step6(s, xv[q].x, c1, c2, c3);
        step6(s, xv[q].y, c1, c2, c3);
        step6(s, xv[q].z, c1, c2, c3);
        step6(s, xv[q].w, c1, c2, c3);
    }
    #pragma unroll
    for (int i = 0; i < 6; ++i) dl[t * 7 + i] = s[i];

    // ---- A^64 via 6 LDS squarings (threads 0..35 work) ----
    if (t < 6) {
        float e[6] = {0.f, 0.f, 0.f, 0.f, 0.f, 0.f};
        e[t] = 1.0f;
        step6(e, 0.0f, c1, c2, c3);              // column t of A
        #pragma unroll
        for (int i = 0; i < 6; ++i) M[i * 6 + t] = e[i];
    }
    __syncthreads();                              // covers dl + M writes
    for (int it = 0; it < LOG2C; ++it) {
        float acc = 0.f;
        if (t < 36) {
            int i = t / 6, j = t - 6 * (t / 6);
            #pragma unroll
            for (int q = 0; q < 6; ++q) acc = fmaf(M[i * 6 + q], M[q * 6 + j], acc);
        }
        __syncthreads();
        if (t < 36) M[t] = acc;
        __syncthreads();
    }
    float a[36];
    #pragma unroll
    for (int i = 0; i < 36; ++i) a[i] = rfl(M[i]);   // wave-uniform -> SGPR

    // ---- truncated Horner scan over predecessors (oldest -> newest) ----
    float t6[6] = {0.f, 0.f, 0.f, 0.f, 0.f, 0.f};
    int m0 = t - MTERM; if (m0 < 0) m0 = 0;
    for (int m = m0; m < t; ++m) {
        float dm[6];
        #pragma unroll
        for (int i = 0; i < 6; ++i) dm[i] = dl[m * 7 + i];
        float nt6[6];
        #pragma unroll
        for (int i = 0; i < 6; ++i) {
            float acc = dm[i];
            #pragma unroll
            for (int j = 0; j < 6; ++j) acc = fmaf(a[i * 6 + j], t6[j], acc);
            nt6[i] = acc;
        }
        #pragma unroll
        for (int i = 0; i < 6; ++i) t6[i] = nt6[i];
    }

    // ---- pass 2: re-run from composed start state, in place ----
    #pragma unroll
    for (int q = 0; q < 16; ++q) {
        float4 v = xv[q];
        v.x = step6(t6, v.x, c1, c2, c3);
        v.y = step6(t6, v.y, c1, c2, c3);
        v.z = step6(t6, v.z, c1, c2, c3);
        v.w = step6(t6, v.w, c1, c2, c3);
        xv[q] = v;
    }

    // ---- burst store (no compute interleaved -> lines go fully dirty fast)
    if (emit) {
        float4* sp = (float4*)(out + (long long)r * T_LEN + (long long)c * CHUNK);
        #pragma unroll
        for (int q = 0; q < 16; ++q) sp[q] = xv[q];
    }
}

extern "C" void kernel_launch(void* const* d_in, const int* in_sizes, int n_in,
                              void* d_out, int out_size, void* d_ws, size_t ws_size,
                              hipStream_t stream) {
    const float* x  = (const float*)d_in[0];
    const float* lg = (const float*)d_in[1];
    const float* mg = (const float*)d_in[2];
    const float* mf = (const float*)d_in[3];
    const float* mq = (const float*)d_in[4];
    const float* hg = (const float*)d_in[5];
    float* out = (float*)d_out;

    hipLaunchKernelGGL(k_fused, dim3(NBLK), dim3(NT), 0, stream,
                       x, lg, mg, mf, mq, hg, out);
}